// Round 3
// baseline (119.604 us; speedup 1.0000x reference)
//
#include <hip/hip_runtime.h>
#include <math.h>

#define NP 8192
#define SEQ 4
#define KNN 16
#define R2 1.0f
#define NBLK (NP / 4)                       // 2048 blocks, 1 wave per point
#define SCALE (1.0f / (float)(SEQ * NP * KNN))

// d_ws layout (bytes):
//   [0,     8192)  float partial[NBLK]
//   [8192, 12288)  int cnt1[64] strided 16 ints (one counter per 64B line)
//   [12288,12292)  int cnt2
// kernel_launch memsets [8192, 12352) to zero each call (graph-safe).

__global__ __launch_bounds__(256) void ballq_fused(
    const float* __restrict__ xyz,   // [NP,3]
    const float* __restrict__ pf,    // [SEQ,NP,3]
    float* __restrict__ partial,     // ws
    int* __restrict__ cnt1,          // ws + 8192
    int* __restrict__ cnt2,          // ws + 12288
    float* __restrict__ out)         // d_out[1]
{
    const int lane = threadIdx.x & 63;
    const int wv   = threadIdx.x >> 6;
    const int i    = (blockIdx.x << 2) + wv;   // query point

    const float xi = xyz[3 * i + 0];
    const float yi = xyz[3 * i + 1];
    const float zi = xyz[3 * i + 2];

    int myNbr = -1;   // lane c (c<16) owns the c-th in-radius index
    int cnt   = 0;    // wave-uniform hit count

    float ax[4], ay[4], az[4], bx[4], by[4], bz[4];

    // Load a 256-candidate window (4 per lane). Wrapped index: the wasted
    // past-the-end prefetch reads window 0 again (harmless, L1-hot).
    auto loadw = [&](int base, float* px, float* py, float* pz) {
#pragma unroll
        for (int u = 0; u < 4; ++u) {
            const int j = (base + (u << 6) + lane) & (NP - 1);
            px[u] = xyz[3 * j + 0];
            py[u] = xyz[3 * j + 1];
            pz[u] = xyz[3 * j + 2];
        }
    };

    // Process one window: 4 ballots; hit ranks via mbcnt; route hit #r to
    // lane r with ds_permute (push). Lane order within a ballot == ascending
    // candidate index, so hits arrive in exact reference scan order.
    auto procw = [&](int base, const float* px, const float* py, const float* pz) {
#pragma unroll
        for (int u = 0; u < 4; ++u) {
            const float dx = px[u] - xi;
            const float dy = py[u] - yi;
            const float dz = pz[u] - zi;
            const bool hit = dx * dx + dy * dy + dz * dz < R2;
            const unsigned long long m = __ballot(hit);
            const unsigned mlo = (unsigned)m, mhi = (unsigned)(m >> 32);
            const int rank = __builtin_amdgcn_mbcnt_hi(
                                 mhi, __builtin_amdgcn_mbcnt_lo(mlo, 0));
            const int pc = __popcll(m);          // wave-uniform
            int tgt = 63;                        // non-hits (and overflow) dump to lane 63
            if (hit) {
                const int t = cnt + rank;
                tgt = t < 63 ? t : 63;           // clamp: ds_permute addr wraps at 64
            }
            const int cj  = base + (u << 6) + lane;
            const int got = __builtin_amdgcn_ds_permute(tgt << 2, cj);
            if (lane >= cnt && lane < cnt + pc && lane < KNN) myNbr = got;
            cnt += pc;
        }
    };

    // Ping-pong pipeline: loads for window W+1 issue before processing W,
    // with no register copies (so no same-iteration vmcnt(0) drain).
    loadw(0, ax, ay, az);
    int base = 0;
    for (;;) {
        loadw(base + 256, bx, by, bz);
        procw(base, ax, ay, az);
        if (cnt >= KNN || base + 256 >= NP) break;
        loadw(base + 512, ax, ay, az);
        procw(base + 256, bx, by, bz);
        if (cnt >= KNN || base + 512 >= NP) break;
        base += 512;
    }
    // Pad: if total hits < 16 we scanned everything, so lane0 holds hit #0
    // (self-distance 0 guarantees >=1 hit). If cnt>=16, no padding needed.
    const int firstHit = __shfl(myNbr, 0);
    if (myNbr < 0) myNbr = firstHit;

    // Phase 2: lane = k + 16*s -> one (seq s, neighbor k) distance term.
    const int k = lane & 15;
    const int s = lane >> 4;
    const int j = __shfl(myNbr, k);
    const size_t oi = ((size_t)s * NP + i) * 3;
    const size_t oj = ((size_t)s * NP + j) * 3;
    const float dx = pf[oi + 0] - pf[oj + 0];
    const float dy = pf[oi + 1] - pf[oj + 1];
    const float dz = pf[oi + 2] - pf[oj + 2];
    float d = sqrtf(fmaxf(dx * dx + dy * dy + dz * dz, 1e-24f));

#pragma unroll
    for (int off = 32; off > 0; off >>= 1) d += __shfl_xor(d, off);

    __shared__ float sacc[4];
    __shared__ int lastFlag;
    if (lane == 0) sacc[wv] = d;
    if (threadIdx.x == 0) lastFlag = 0;
    __syncthreads();

    // Per-block partial + two-level completion counters (max same-address
    // atomic chain = 64, vs 2048 in round 2's single atomicAdd target).
    if (threadIdx.x == 0) {
        const float p = sacc[0] + sacc[1] + sacc[2] + sacc[3];
        __hip_atomic_store(&partial[blockIdx.x], p, __ATOMIC_RELEASE,
                           __HIP_MEMORY_SCOPE_AGENT);
        const int old1 = __hip_atomic_fetch_add(&cnt1[(blockIdx.x & 63) << 4], 1,
                                                __ATOMIC_ACQ_REL,
                                                __HIP_MEMORY_SCOPE_AGENT);
        if (old1 == 31) {   // last block of this group of 32
            const int old2 = __hip_atomic_fetch_add(cnt2, 1, __ATOMIC_ACQ_REL,
                                                    __HIP_MEMORY_SCOPE_AGENT);
            if (old2 == 63) lastFlag = 1;   // last block overall
        }
    }
    __syncthreads();

    if (lastFlag) {       // exactly one block: reduce all partials -> out
        __threadfence();
        float ssum = 0.0f;
        for (int t = threadIdx.x; t < NBLK; t += 256)
            ssum += __hip_atomic_load(&partial[t], __ATOMIC_RELAXED,
                                      __HIP_MEMORY_SCOPE_AGENT);
#pragma unroll
        for (int off = 32; off > 0; off >>= 1) ssum += __shfl_xor(ssum, off);
        __shared__ float fin[4];
        if (lane == 0) fin[wv] = ssum;
        __syncthreads();
        if (threadIdx.x == 0)
            out[0] = (fin[0] + fin[1] + fin[2] + fin[3]) * SCALE;
    }
}

extern "C" void kernel_launch(void* const* d_in, const int* in_sizes, int n_in,
                              void* d_out, int out_size, void* d_ws, size_t ws_size,
                              hipStream_t stream) {
    const float* xyz = (const float*)d_in[0];  // pc_source [1,8192,3]
    const float* pf  = (const float*)d_in[1];  // pred_flow [4,8192,3]
    float* partial   = (float*)d_ws;
    int*   cnt1      = (int*)((char*)d_ws + 8192);
    int*   cnt2      = (int*)((char*)d_ws + 12288);
    float* out       = (float*)d_out;

    // Zero only the counters (d_ws is poisoned 0xAA before every launch).
    hipMemsetAsync((char*)d_ws + 8192, 0, 4160, stream);
    ballq_fused<<<NBLK, 256, 0, stream>>>(xyz, pf, partial, cnt1, cnt2, out);
}

// Round 4
// 78.169 us; speedup vs baseline: 1.5301x; 1.5301x over previous
//
#include <hip/hip_runtime.h>
#include <math.h>

#define NP 8192
#define SEQ 4
#define KNN 16
#define R2 1.0f
#define NBLK (NP / 4)                  // 2048 blocks, 1 wave per point
#define WSZ 1024                       // candidates scanned per wave-iteration
#define CPL 16                         // candidates per lane (contiguous)
#define SCALE (1.0f / (float)(SEQ * NP * KNN))

// One wave per query point; block = 256 = 4 waves.
// Per window: 16 contiguous candidates/lane via 12 aligned float4 loads ->
// per-lane 16-bit hit mask -> wave prefix-sum of popcounts -> in-rank hits
// (global rank < 16) written to a per-wave LDS slot array -> lanes 0..15
// read their slot. (lane, bit) order == ascending candidate index, matching
// the reference's scan order exactly. Stragglers: 8 windows max (vs 32).
__global__ __launch_bounds__(256) void ballq_main(
    const float* __restrict__ xyz,   // [NP,3]
    const float* __restrict__ pf,    // [SEQ,NP,3]
    float* __restrict__ partial)     // [NBLK]
{
    const int lane = threadIdx.x & 63;
    const int wv   = threadIdx.x >> 6;
    const int i    = (blockIdx.x << 2) + wv;

    const float xi = xyz[3 * i + 0];
    const float yi = xyz[3 * i + 1];
    const float zi = xyz[3 * i + 2];

    __shared__ int slots[4][KNN];    // per-wave first-16 hit indices

    int myNbr = -1;
    int cnt   = 0;                   // wave-uniform hits found so far

    for (int base = 0; base < NP; base += WSZ) {
        // Lane l covers candidates [base+16l, base+16l+16): 48 floats,
        // 12 aligned float4 loads (3*base and 48*l both divisible by 4).
        float f[48];
        const float4* p = (const float4*)xyz + ((3 * base) >> 2) + 12 * lane;
#pragma unroll
        for (int j = 0; j < 12; ++j) ((float4*)f)[j] = p[j];

        unsigned m = 0;
#pragma unroll
        for (int u = 0; u < CPL; ++u) {
            const float dx = f[3 * u + 0] - xi;
            const float dy = f[3 * u + 1] - yi;
            const float dz = f[3 * u + 2] - zi;
            m |= (unsigned)(dx * dx + dy * dy + dz * dz < R2) << u;
        }

        // Wave-wide exclusive prefix of per-lane hit counts.
        const int c = __popc(m);
        int pfx = c;
#pragma unroll
        for (int off = 1; off < 64; off <<= 1) {
            const int t = __shfl_up(pfx, off);
            if (lane >= off) pfx += t;
        }
        const int excl  = pfx - c;
        const int total = __shfl(pfx, 63);

        // Write this lane's in-rank hits (ranks ascend within the lane,
        // so break at the first out-of-range rank).
        unsigned mm = m;
        int r = 0;
        while (mm) {
            const int rank = cnt + excl + r;
            if (rank >= KNN) break;
            const int b = __builtin_ctz(mm);
            slots[wv][rank] = base + CPL * lane + b;
            mm &= mm - 1;
            ++r;
        }

        const int newcnt = cnt + total;
        if (lane >= cnt && lane < KNN && lane < newcnt)
            myNbr = slots[wv][lane];          // same-wave RAW on LDS: compiler
        cnt = newcnt;                          // inserts the lgkmcnt wait
        if (cnt >= KNN) break;                 // wave-uniform early exit
    }
    // Fewer than 16 total hits: pad with hit #0 (self guarantees >=1).
    const int firstHit = __shfl(myNbr, 0);
    if (myNbr < 0) myNbr = firstHit;

    // Phase 2: lane = k + 16*s -> one (seq s, neighbor k) distance term.
    const int k = lane & 15;
    const int s = lane >> 4;
    const int j = __shfl(myNbr, k);
    const size_t oi = ((size_t)s * NP + i) * 3;
    const size_t oj = ((size_t)s * NP + j) * 3;
    const float dx = pf[oi + 0] - pf[oj + 0];
    const float dy = pf[oi + 1] - pf[oj + 1];
    const float dz = pf[oi + 2] - pf[oj + 2];
    float d = sqrtf(fmaxf(dx * dx + dy * dy + dz * dz, 1e-24f));

#pragma unroll
    for (int off = 32; off > 0; off >>= 1) d += __shfl_xor(d, off);

    __shared__ float sacc[4];
    if (lane == 0) sacc[wv] = d;
    __syncthreads();
    if (threadIdx.x == 0)
        partial[blockIdx.x] = sacc[0] + sacc[1] + sacc[2] + sacc[3];
}

__global__ __launch_bounds__(256) void ballq_reduce(
    const float* __restrict__ partial, float* __restrict__ out)
{
    float s = 0.0f;
    for (int t = threadIdx.x; t < NBLK; t += 256) s += partial[t];
#pragma unroll
    for (int off = 32; off > 0; off >>= 1) s += __shfl_xor(s, off);
    __shared__ float w[4];
    const int lane = threadIdx.x & 63, wv = threadIdx.x >> 6;
    if (lane == 0) w[wv] = s;
    __syncthreads();
    if (threadIdx.x == 0)
        out[0] = (w[0] + w[1] + w[2] + w[3]) * SCALE;
}

extern "C" void kernel_launch(void* const* d_in, const int* in_sizes, int n_in,
                              void* d_out, int out_size, void* d_ws, size_t ws_size,
                              hipStream_t stream) {
    const float* xyz = (const float*)d_in[0];  // pc_source [1,8192,3]
    const float* pf  = (const float*)d_in[1];  // pred_flow [4,8192,3]
    float* partial   = (float*)d_ws;           // NBLK floats, fully overwritten
    float* out       = (float*)d_out;

    ballq_main<<<NBLK, 256, 0, stream>>>(xyz, pf, partial);
    ballq_reduce<<<1, 256, 0, stream>>>(partial, out);
}